// Round 10
// baseline (171.923 us; speedup 1.0000x reference)
//
#include <hip/hip_runtime.h>
#include <stdint.h>

#define M_DIM 4096
#define N_DIM 4096
#define K_DIM 4096

typedef int i32x4 __attribute__((ext_vector_type(4)));

// ---- Kernel 1 (fused): blocks 0..4095: x per-row quant; blocks 4096..5119: wmax ----
__global__ void prep_kernel(const float* __restrict__ w,
                            const float* __restrict__ x,
                            unsigned int* __restrict__ out_bits,
                            char* __restrict__ xq,
                            float* __restrict__ xsinv) {
    __shared__ float sred[4];
    if (blockIdx.x < 4096) {
        // ---- x -> int8, per-row scale; xsinv[row] = rowmax/127 ----
        const int row = blockIdx.x;
        const int t = threadIdx.x;
        const float4* xr = (const float4*)(x + (size_t)row * K_DIM);
        float4 v[4];
        float m = 0.f;
        #pragma unroll
        for (int i = 0; i < 4; ++i) {
            v[i] = xr[t * 4 + i];
            m = fmaxf(m, fmaxf(fmaxf(fabsf(v[i].x), fabsf(v[i].y)),
                               fmaxf(fabsf(v[i].z), fabsf(v[i].w))));
        }
        for (int off = 32; off > 0; off >>= 1) m = fmaxf(m, __shfl_xor(m, off));
        if ((t & 63) == 0) sred[t >> 6] = m;
        __syncthreads();
        m = fmaxf(fmaxf(fmaxf(sred[0], sred[1]), fmaxf(sred[2], sred[3])), 1e-30f);
        if (t == 0) xsinv[row] = m * (1.0f / 127.0f);
        const float scale = 127.0f / m;
        int4 o;
        int* op = (int*)&o;
        #pragma unroll
        for (int i = 0; i < 4; ++i) {
            int a = (int)rintf(v[i].x * scale);
            int b = (int)rintf(v[i].y * scale);
            int c = (int)rintf(v[i].z * scale);
            int d = (int)rintf(v[i].w * scale);
            op[i] = (a & 0xff) | ((b & 0xff) << 8) | ((c & 0xff) << 16) | (d << 24);
        }
        *(int4*)(xq + (size_t)row * K_DIM + t * 16) = o;
    } else {
        // ---- wmax = max|W| -> uint bits, one atomic per block ----
        int tid = (blockIdx.x - 4096) * blockDim.x + threadIdx.x;
        const int stride = 1024 * 256;
        const int n4 = (N_DIM * K_DIM) / 4;
        const float4* w4 = (const float4*)w;
        float m = 0.f;
        for (int i = tid; i < n4; i += stride) {
            float4 a = w4[i];
            m = fmaxf(m, fmaxf(fmaxf(fabsf(a.x), fabsf(a.y)), fmaxf(fabsf(a.z), fabsf(a.w))));
        }
        for (int off = 32; off > 0; off >>= 1) m = fmaxf(m, __shfl_xor(m, off));
        if ((threadIdx.x & 63) == 0) sred[threadIdx.x >> 6] = m;
        __syncthreads();
        if (threadIdx.x == 0) {
            m = fmaxf(fmaxf(sred[0], sred[1]), fmaxf(sred[2], sred[3]));
            atomicMax(out_bits, __float_as_uint(m));  // |w|>=0: uint order == float order
        }
    }
}

// ---- Kernel 2: W -> int8 (trunc, exact reference grid) ----
__global__ void wquant_kernel(const float* __restrict__ w,
                              const unsigned int* __restrict__ mb,
                              int* __restrict__ wq4, int n4) {
    const float wscale = 127.0f / __uint_as_float(mb[0]);
    int tid = blockIdx.x * blockDim.x + threadIdx.x;
    int stride = gridDim.x * blockDim.x;
    const float4* w4 = (const float4*)w;
    for (int i = tid; i < n4; i += stride) {
        float4 a = w4[i];
        int w0 = (int)fminf(fmaxf(truncf(a.x * wscale), -127.f), 127.f);
        int w1 = (int)fminf(fmaxf(truncf(a.y * wscale), -127.f), 127.f);
        int w2 = (int)fminf(fmaxf(truncf(a.z * wscale), -127.f), 127.f);
        int w3 = (int)fminf(fmaxf(truncf(a.w * wscale), -127.f), 127.f);
        wq4[i] = (w0 & 0xff) | ((w1 & 0xff) << 8) | ((w2 & 0xff) << 16) | (w3 << 24);
    }
}

// ---- Kernel 3: 256x256 i8 GEMM, 4 BIG WAVES (128x128 each, 1 wave/SIMD).
// Fixes vs R9: (a) global_load_lds dest is WAVE-UNIFORM (i*4096 + wave*1024; HW adds
// lane*16 -> same bytes as t*16, but no divergent lds_ptr UB); (b) accumulators in
// AGPRs via "+a" asm constraint (canonical v_mfma a,v,v,a) -> arch-VGPR pressure ~170.
// LDS 128KB: A dbuf @0/32K, B dbuf @64K/96K; XOR swizzle byte^=(row&7)<<4 both-sides.
#define BAR()   __builtin_amdgcn_s_barrier()
#define FENCE() __builtin_amdgcn_sched_barrier(0)

#define MFMA_I8(ACC, AF, BF) \
    asm("v_mfma_i32_16x16x64_i8 %0, %1, %2, %0" : "+a"(ACC) : "v"(AF), "v"(BF))

__global__ __launch_bounds__(256, 1) void gemm_i8(
    const char* __restrict__ A,      // xq row-major [M][K]
    const char* __restrict__ B,      // wq row-major [N][K]
    const unsigned int* __restrict__ mb,
    const float* __restrict__ xsinv,
    const float* __restrict__ bias,
    float* __restrict__ C)
{
    __shared__ __align__(16) char sM[131072];

    int bid = (blockIdx.x & 7) * 32 + (blockIdx.x >> 3);   // XCD-bijective (nwg=256)
    const int bm = bid >> 4;
    const int bn = bid & 15;

    const int t    = threadIdx.x;
    const int wave = t >> 6;        // 0..3
    const int lane = t & 63;
    const int wm   = wave >> 1;     // 0..1 : 128-row half
    const int wn   = wave & 1;      // 0..1 : 128-col half

    i32x4 acc[8][8] = {};           // 128x128 per wave: [m][n] 16x16 tiles (AGPRs)

    // LDS-read bases. frag(m,kk): row = wm*128 + m*16 + (lane&15);
    // byte = row*128 + (kk*64 + (lane>>4)<<4) ^ ((lane&7)<<4)   [row&7 == lane&7]
    const int chunk = (((lane >> 4) << 4) ^ ((lane & 7) << 4));
    const int lbA = ((lane & 15) << 7) + chunk + wm * 16384;            // + m*2048 ^ kk*64
    const int lbB = ((lane & 15) << 7) + chunk + wn * 16384 + 65536;    // + n*2048 ^ kk*64

    // Staging: per 128-row half, thread t covers rows {i*32 + (t>>3)}, slot (t&7);
    // source chunk pre-swizzled: LDS[row][c] = SRC[row][c ^ (row&7)], row&7 == (t>>3)&7.
    const int srow = t >> 3;                      // 0..31
    const int cch  = (t & 7) ^ (srow & 7);
    const char* Abase = A + (size_t)(bm * 256 + srow) * K_DIM + cch * 16;
    const char* Bbase = B + (size_t)(bn * 256 + srow) * K_DIM + cch * 16;
    const int wave_lds = wave * 1024;             // uniform; HW adds lane*16

    // Stage one 128-row half (16KB) of A(REG=0)/B(REG=65536): 4 gload_lds/thread.
    // Dest pointer is WAVE-UNIFORM; lane*16 added by hardware (m104/m108 semantics).
#define STAGEH(SRC, REG, H, KT, BUF) do {                                               \
        _Pragma("unroll") for (int i = 0; i < 4; ++i) {                                 \
            const char* _s = SRC + (size_t)((H)*128 + i*32) * K_DIM + ((KT) << 7);      \
            char* _d = sM + (REG) + (BUF)*32768 + (H)*16384 + i*4096 + wave_lds;        \
            __builtin_amdgcn_global_load_lds(                                           \
                (const __attribute__((address_space(1))) void*)_s,                      \
                (__attribute__((address_space(3))) void*)_d, 16, 0, 0);                 \
        }                                                                               \
    } while(0)

    // Load one K-chunk (kk) of all frags: 8 A + 8 B ds_read_b128, each read ONCE.
#define LDC(KK, BUF, AV, BV) do {                                                       \
        _Pragma("unroll") for (int m = 0; m < 8; ++m)                                   \
            AV[m] = *(const i32x4*)(sM + (BUF)*32768 + m*2048 + (lbA ^ ((KK)*64)));     \
        _Pragma("unroll") for (int n = 0; n < 8; ++n)                                   \
            BV[n] = *(const i32x4*)(sM + (BUF)*32768 + n*2048 + (lbB ^ ((KK)*64)));     \
    } while(0)

    // 64 independent MFMA for one K-chunk.
#define MMAC(AV, BV)                                                                    \
        _Pragma("unroll") for (int m = 0; m < 8; ++m)                                   \
        _Pragma("unroll") for (int n = 0; n < 8; ++n)                                   \
            MFMA_I8(acc[m][n], AV[m], BV[n]);

    // One K-tile: stage next tile (KN->OBUF) first, read+compute current (BUF).
#define TILE(BUF, OBUF, KN) do {                                                        \
        STAGEH(Abase, 0,     0, KN, OBUF);                                              \
        STAGEH(Abase, 0,     1, KN, OBUF);                                              \
        STAGEH(Bbase, 65536, 0, KN, OBUF);                                              \
        STAGEH(Bbase, 65536, 1, KN, OBUF);      /* 16 vmem-lds */                       \
        LDC(0, BUF, a0, b0);                                                            \
        LDC(1, BUF, a1, b1);                    /* 32 ds_read; lgkm auto-counted */     \
        __builtin_amdgcn_s_setprio(1);                                                  \
        MMAC(a0, b0);                                                                   \
        MMAC(a1, b1);                                                                   \
        __builtin_amdgcn_s_setprio(0);                                                  \
        asm volatile("s_waitcnt vmcnt(0)");     /* stages issued full tile ago */       \
        BAR();                                                                          \
        FENCE();                                                                        \
    } while(0)

    // Prologue: stage tile 0 -> buf0.
    STAGEH(Abase, 0,     0, 0, 0);
    STAGEH(Abase, 0,     1, 0, 0);
    STAGEH(Bbase, 65536, 0, 0, 0);
    STAGEH(Bbase, 65536, 1, 0, 0);
    asm volatile("s_waitcnt vmcnt(0)");
    BAR();
    FENCE();

    i32x4 a0[8], a1[8], b0[8], b1[8];

    for (int it = 0; it < 16; ++it) {
        TILE(0, 1, (2 * it + 1) & 31);
        TILE(1, 0, (2 * it + 2) & 31);
    }

    const float wdq = __uint_as_float(mb[0]) * (1.0f / 127.0f);

    // Epilogue: D layout (m89): col = lane&15, row = (lane>>4)*4 + reg.
    // C = acc * (wdq * xsinv[row]) + bias[col]
    #pragma unroll
    for (int m = 0; m < 8; ++m) {
        const int grow0 = bm * 256 + wm * 128 + m * 16 + (lane >> 4) * 4;
        float rs[4];
        #pragma unroll
        for (int rg = 0; rg < 4; ++rg) rs[rg] = xsinv[grow0 + rg] * wdq;
        #pragma unroll
        for (int n = 0; n < 8; ++n) {
            const int gcol = bn * 256 + wn * 128 + n * 16 + (lane & 15);
            const float bv = bias[gcol];
            #pragma unroll
            for (int rg = 0; rg < 4; ++rg)
                C[(size_t)(grow0 + rg) * N_DIM + gcol] = (float)acc[m][n][rg] * rs[rg] + bv;
        }
    }

#undef STAGEH
#undef LDC
#undef MMAC
#undef TILE
}

extern "C" void kernel_launch(void* const* d_in, const int* in_sizes, int n_in,
                              void* d_out, int out_size, void* d_ws, size_t ws_size,
                              hipStream_t stream) {
    const float* x    = (const float*)d_in[0];   // [4096, 4096]
    const float* w    = (const float*)d_in[1];   // [4096, 4096]
    const float* bias = (const float*)d_in[2];   // [4096]
    float* out = (float*)d_out;

    unsigned int* maxbits = (unsigned int*)d_ws;            // [0]=wmax bits
    float* xsinv = (float*)((char*)d_ws + 256);             // [4096]
    char*  xq    = (char*)d_ws + 32768;                     // 16 MB
    char*  wq    = (char*)d_ws + 32768 + (size_t)M_DIM * K_DIM;

    hipMemsetAsync(d_ws, 0, 8, stream);

    const int n4 = (N_DIM * K_DIM) / 4;
    prep_kernel<<<4096 + 1024, 256, 0, stream>>>(w, x, maxbits, xq, xsinv);
    wquant_kernel<<<2048, 256, 0, stream>>>(w, maxbits, (int*)wq, n4);

    const int grid = (M_DIM / 256) * (N_DIM / 256);  // 256
    gemm_i8<<<grid, 256, 0, stream>>>(xq, wq, maxbits, xsinv, bias, out);
}

// Round 11
// 115.417 us; speedup vs baseline: 1.4896x; 1.4896x over previous
//
#include <hip/hip_runtime.h>
#include <stdint.h>

#define M_DIM 4096
#define N_DIM 4096
#define K_DIM 4096

typedef int i32x4 __attribute__((ext_vector_type(4)));

// ---- Kernel 1 (fused): blocks 0..4095: x per-row quant; blocks 4096..5119: wmax ----
__global__ void prep_kernel(const float* __restrict__ w,
                            const float* __restrict__ x,
                            unsigned int* __restrict__ out_bits,
                            char* __restrict__ xq,
                            float* __restrict__ xsinv) {
    __shared__ float sred[4];
    if (blockIdx.x < 4096) {
        // ---- x -> int8, per-row scale; xsinv[row] = rowmax/127 ----
        const int row = blockIdx.x;
        const int t = threadIdx.x;
        const float4* xr = (const float4*)(x + (size_t)row * K_DIM);
        float4 v[4];
        float m = 0.f;
        #pragma unroll
        for (int i = 0; i < 4; ++i) {
            v[i] = xr[t * 4 + i];
            m = fmaxf(m, fmaxf(fmaxf(fabsf(v[i].x), fabsf(v[i].y)),
                               fmaxf(fabsf(v[i].z), fabsf(v[i].w))));
        }
        for (int off = 32; off > 0; off >>= 1) m = fmaxf(m, __shfl_xor(m, off));
        if ((t & 63) == 0) sred[t >> 6] = m;
        __syncthreads();
        m = fmaxf(fmaxf(fmaxf(sred[0], sred[1]), fmaxf(sred[2], sred[3])), 1e-30f);
        if (t == 0) xsinv[row] = m * (1.0f / 127.0f);
        const float scale = 127.0f / m;
        int4 o;
        int* op = (int*)&o;
        #pragma unroll
        for (int i = 0; i < 4; ++i) {
            int a = (int)rintf(v[i].x * scale);
            int b = (int)rintf(v[i].y * scale);
            int c = (int)rintf(v[i].z * scale);
            int d = (int)rintf(v[i].w * scale);
            op[i] = (a & 0xff) | ((b & 0xff) << 8) | ((c & 0xff) << 16) | (d << 24);
        }
        *(int4*)(xq + (size_t)row * K_DIM + t * 16) = o;
    } else {
        // ---- wmax = max|W| -> uint bits, one atomic per block ----
        int tid = (blockIdx.x - 4096) * blockDim.x + threadIdx.x;
        const int stride = 1024 * 256;
        const int n4 = (N_DIM * K_DIM) / 4;
        const float4* w4 = (const float4*)w;
        float m = 0.f;
        for (int i = tid; i < n4; i += stride) {
            float4 a = w4[i];
            m = fmaxf(m, fmaxf(fmaxf(fabsf(a.x), fabsf(a.y)), fmaxf(fabsf(a.z), fabsf(a.w))));
        }
        for (int off = 32; off > 0; off >>= 1) m = fmaxf(m, __shfl_xor(m, off));
        if ((threadIdx.x & 63) == 0) sred[threadIdx.x >> 6] = m;
        __syncthreads();
        if (threadIdx.x == 0) {
            m = fmaxf(fmaxf(sred[0], sred[1]), fmaxf(sred[2], sred[3]));
            atomicMax(out_bits, __float_as_uint(m));  // |w|>=0: uint order == float order
        }
    }
}

// ---- Kernel 2: W -> int8 (trunc, exact reference grid) ----
__global__ void wquant_kernel(const float* __restrict__ w,
                              const unsigned int* __restrict__ mb,
                              int* __restrict__ wq4, int n4) {
    const float wscale = 127.0f / __uint_as_float(mb[0]);
    int tid = blockIdx.x * blockDim.x + threadIdx.x;
    int stride = gridDim.x * blockDim.x;
    const float4* w4 = (const float4*)w;
    for (int i = tid; i < n4; i += stride) {
        float4 a = w4[i];
        int w0 = (int)fminf(fmaxf(truncf(a.x * wscale), -127.f), 127.f);
        int w1 = (int)fminf(fmaxf(truncf(a.y * wscale), -127.f), 127.f);
        int w2 = (int)fminf(fmaxf(truncf(a.z * wscale), -127.f), 127.f);
        int w3 = (int)fminf(fmaxf(truncf(a.w * wscale), -127.f), 127.f);
        wq4[i] = (w0 & 0xff) | ((w1 & 0xff) << 8) | ((w2 & 0xff) << 16) | (w3 << 24);
    }
}

// ---- Kernel 3: 256x256 i8 GEMM, 8 waves (2Mx4N of 128x64), R6 structure with
// GROUPED READ INTERLEAVE: reads issued in FENCE-pinned groups so each group is
// serviced under the previous 16-MFMA cluster; STAGEs issued late (Q11) so their
// LDS-writes land after the read burst. One vmcnt(0)+barrier per K-tile.
// LDS 128KB: A dbuf @0/32K, B dbuf @64K/96K; XOR swizzle byte^=(row&7)<<4 both-sides.
#define BAR()   __builtin_amdgcn_s_barrier()
#define FENCE() __builtin_amdgcn_sched_barrier(0)

#define MFMA_I8(ACC, AF, BF) \
    asm("v_mfma_i32_16x16x64_i8 %0, %1, %2, %0" : "+v"(ACC) : "v"(AF), "v"(BF))

__global__ __launch_bounds__(512, 2) void gemm_i8(
    const char* __restrict__ A,
    const char* __restrict__ B,
    const unsigned int* __restrict__ mb,
    const float* __restrict__ xsinv,
    const float* __restrict__ bias,
    float* __restrict__ C)
{
    __shared__ __align__(16) char sM[131072];

    int bid = (blockIdx.x & 7) * 32 + (blockIdx.x >> 3);   // XCD-bijective (nwg=256)
    const int bm = bid >> 4;
    const int bn = bid & 15;

    const int t    = threadIdx.x;
    const int wave = t >> 6;
    const int lane = t & 63;
    const int wm   = wave >> 2;     // 0..1
    const int wn   = wave & 3;      // 0..3

    i32x4 acc[2][2][4][2] = {};     // [h][g][mi][ni]

    // LDS-read bases (swizzle folded: row&7 == lane&7 for all row-blocks used)
    const int chunk = (((lane >> 4) << 4) ^ ((lane & 7) << 4));
    const int lbA0 = ((lane & 15) << 7) + chunk + wm * 8192;
    const int lbA1 = lbA0 ^ 64;
    const int lbB0 = ((lane & 15) << 7) + chunk + wn * 4096 + 65536;
    const int lbB1 = lbB0 ^ 64;

    // Staging: thread t owns linear LDS slot t*16 (+8192 for 2nd 64-row block);
    // source chunk pre-swizzled so LDS[row][c] = SRC[row][c^(row&7)].
    const int srow = t >> 3;
    const int cch  = (t & 7) ^ (srow & 7);
    const char* Abase = A + (size_t)(bm * 256 + srow) * K_DIM + cch * 16;
    const char* Bbase = B + (size_t)(bn * 256 + srow) * K_DIM + cch * 16;
    const int wave_lds = wave * 1024;    // wave-uniform dest; HW adds lane*16

#define STAGE(SRC, REG, H, KT, BUF) do {                                                \
        const char* _s = SRC + (H) * (128 * K_DIM) + ((KT) << 7);                       \
        char* _d = sM + (REG) + (BUF) * 32768 + (H) * 16384 + wave_lds;                 \
        __builtin_amdgcn_global_load_lds(                                               \
            (const __attribute__((address_space(1))) void*)_s,                          \
            (__attribute__((address_space(3))) void*)_d, 16, 0, 0);                     \
        __builtin_amdgcn_global_load_lds(                                               \
            (const __attribute__((address_space(1))) void*)(_s + (size_t)64 * K_DIM),   \
            (__attribute__((address_space(3))) void*)(_d + 8192), 16, 0, 0);            \
    } while(0)

#define LDA(H, BUF, AF) do {                                                            \
        _Pragma("unroll") for (int mi = 0; mi < 4; ++mi) {                              \
            AF[mi][0] = *(const i32x4*)(sM + (BUF)*32768 + (H)*16384 + mi*2048 + lbA0); \
            AF[mi][1] = *(const i32x4*)(sM + (BUF)*32768 + (H)*16384 + mi*2048 + lbA1); \
        }                                                                               \
    } while(0)

#define LDB(G, BUF, BF) do {                                                            \
        _Pragma("unroll") for (int ni = 0; ni < 2; ++ni) {                              \
            BF[ni][0] = *(const i32x4*)(sM + (BUF)*32768 + (G)*16384 + ni*2048 + lbB0); \
            BF[ni][1] = *(const i32x4*)(sM + (BUF)*32768 + (G)*16384 + ni*2048 + lbB1); \
        }                                                                               \
    } while(0)

    // one C-quadrant x K=128: 16 MFMA, kk-outer (8 indep accs between acc reuse)
#define MMAQ(H, G, AF, BF) do {                                                         \
        __builtin_amdgcn_s_setprio(1);                                                  \
        _Pragma("unroll") for (int kk = 0; kk < 2; ++kk)                                \
        _Pragma("unroll") for (int mi = 0; mi < 4; ++mi)                                \
        _Pragma("unroll") for (int ni = 0; ni < 2; ++ni)                                \
            MFMA_I8(acc[H][G][mi][ni], AF[mi][kk], BF[ni][kk]);                         \
        __builtin_amdgcn_s_setprio(0);                                                  \
    } while(0)

    // One K-tile: grouped reads, each group serviced under the previous MFMA cluster.
#define TILE(BUF, OBUF, KN) do {                                                        \
        LDA(0, BUF, af0); LDB(0, BUF, bf0);      /* group 0: 12 reads (Q00 operands) */ \
        FENCE();                                                                        \
        LDB(1, BUF, bf1);                        /* group 1: 4 reads, under Q00 */      \
        FENCE();                                                                        \
        MMAQ(0, 0, af0, bf0);                    /* waits lgkm<=4 (bf1 in flight) */    \
        LDA(1, BUF, af1);                        /* group 2: 8 reads, under Q01 */      \
        FENCE();                                                                        \
        MMAQ(0, 1, af0, bf1);                    /* waits bf1; af1 in flight */         \
        STAGE(Abase, 0,     0, KN, OBUF);        /* stages late: writes land after */   \
        STAGE(Abase, 0,     1, KN, OBUF);        /*   the read burst, under Q11/Q10 */  \
        STAGE(Bbase, 65536, 0, KN, OBUF);                                               \
        STAGE(Bbase, 65536, 1, KN, OBUF);                                               \
        FENCE();                                                                        \
        MMAQ(1, 1, af1, bf1);                    /* waits af1 */                        \
        FENCE();                                                                        \
        MMAQ(1, 0, af1, bf0);                                                           \
        asm volatile("s_waitcnt vmcnt(0)");      /* stages issued ~1300cy ago */        \
        BAR();                                                                          \
        FENCE();                                                                        \
    } while(0)

    // Prologue: stage tile 0 -> buf0.
    STAGE(Abase, 0,     0, 0, 0);
    STAGE(Abase, 0,     1, 0, 0);
    STAGE(Bbase, 65536, 0, 0, 0);
    STAGE(Bbase, 65536, 1, 0, 0);
    asm volatile("s_waitcnt vmcnt(0)");
    BAR();
    FENCE();

    i32x4 af0[4][2], af1[4][2], bf0[2][2], bf1[2][2];

    for (int it = 0; it < 16; ++it) {
        TILE(0, 1, (2 * it + 1) & 31);
        TILE(1, 0, (2 * it + 2) & 31);
    }

    const float wdq = __uint_as_float(mb[0]) * (1.0f / 127.0f);

    // Epilogue: D layout (m89): col = lane&15, row = (lane>>4)*4 + reg.
    // C = acc * (wdq * xsinv[row]) + bias[col]
    #pragma unroll
    for (int h = 0; h < 2; ++h)
    #pragma unroll
    for (int mi = 0; mi < 4; ++mi) {
        const int grow0 = bm * 256 + h * 128 + wm * 64 + mi * 16 + (lane >> 4) * 4;
        float rs[4];
        #pragma unroll
        for (int rg = 0; rg < 4; ++rg) rs[rg] = xsinv[grow0 + rg] * wdq;
        #pragma unroll
        for (int g = 0; g < 2; ++g)
        #pragma unroll
        for (int ni = 0; ni < 2; ++ni) {
            const int gcol = bn * 256 + g * 128 + wn * 32 + ni * 16 + (lane & 15);
            const float bv = bias[gcol];
            #pragma unroll
            for (int rg = 0; rg < 4; ++rg)
                C[(size_t)(grow0 + rg) * N_DIM + gcol] =
                    (float)acc[h][g][mi][ni][rg] * rs[rg] + bv;
        }
    }

#undef STAGE
#undef LDA
#undef LDB
#undef MMAQ
#undef TILE
}

extern "C" void kernel_launch(void* const* d_in, const int* in_sizes, int n_in,
                              void* d_out, int out_size, void* d_ws, size_t ws_size,
                              hipStream_t stream) {
    const float* x    = (const float*)d_in[0];   // [4096, 4096]
    const float* w    = (const float*)d_in[1];   // [4096, 4096]
    const float* bias = (const float*)d_in[2];   // [4096]
    float* out = (float*)d_out;

    unsigned int* maxbits = (unsigned int*)d_ws;            // [0]=wmax bits
    float* xsinv = (float*)((char*)d_ws + 256);             // [4096]
    char*  xq    = (char*)d_ws + 32768;                     // 16 MB
    char*  wq    = (char*)d_ws + 32768 + (size_t)M_DIM * K_DIM;

    hipMemsetAsync(d_ws, 0, 8, stream);

    const int n4 = (N_DIM * K_DIM) / 4;
    prep_kernel<<<4096 + 1024, 256, 0, stream>>>(w, x, maxbits, xq, xsinv);
    wquant_kernel<<<2048, 256, 0, stream>>>(w, maxbits, (int*)wq, n4);

    const int grid = (M_DIM / 256) * (N_DIM / 256);  // 256
    gemm_i8<<<grid, 512, 0, stream>>>(xq, wq, maxbits, xsinv, bias, out);
}